// Round 13
// baseline (101.943 us; speedup 1.0000x reference)
//
#include <hip/hip_runtime.h>
#include <hip/hip_bf16.h>
#include <math.h>

#define D 300
#define R 5
#define NE 1000000
#define B 32
#define NG 25000
#define NS 25000
#define NROWS 50000
#define NT16 3125      // 16-row j-tiles (50000 = 3125*16)
#define WT 64          // W rows staged per block
#define NGRP 40        // 8-float groups staged per row (k 0..319; >=300 zeroed)
#define HST 324        // LDS row stride in bf16 (648 B; measured 0 conflicts)

typedef __bf16 bf16x8 __attribute__((ext_vector_type(8)));
typedef float f32x4 __attribute__((ext_vector_type(4)));

// ws layout (floats):
//   wsum [0, 48000)  wcnt [48000, 48160)  hcf [48160, 57760)
//   pm2  float2 at 57760: 64 x 3125 -> [57760, 457760)

__device__ __forceinline__ void online_upd(float& m, float& s, float v) {
    if (v > m) { s = s * __expf(m - v) + 1.0f; m = v; }
    else       { s += __expf(v - m); }
}
__device__ __forceinline__ void online_merge(float& m, float& s, float om, float os) {
    float M = fmaxf(m, om);
    s = s * __expf(m - M) + os * __expf(om - M);
    m = M;
}

__global__ void zero_ws(float4* __restrict__ p) {
    int i = blockIdx.x * 256 + threadIdx.x;
    if (i < 14440) p[i] = float4{0.f, 0.f, 0.f, 0.f};  // wsum|wcnt|hcf
}

// Proven (R4-R7): bloom dst scan, LDS-compact matches, coalesced 300-float row-adds.
__global__ __launch_bounds__(256) void scan_accum(
        const int* __restrict__ ei, const int* __restrict__ et,
        const int* __restrict__ cur, const float* __restrict__ x,
        float* __restrict__ wsum, float* __restrict__ wcnt) {
    __shared__ unsigned int tbl[32];
    __shared__ int curl[B];
    __shared__ int lcnt;
    __shared__ int2 loc[64];
    int tid = threadIdx.x;
    if (tid < 32) tbl[tid] = 0u;
    if (tid == 0) lcnt = 0;
    __syncthreads();
    if (tid < B) { int c = cur[tid]; curl[tid] = c; atomicOr(&tbl[(c >> 5) & 31], 1u << (c & 31)); }
    __syncthreads();
    long base = ((long)blockIdx.x * 256 + tid) * 4;
    if (base < NE) {
        int ds4[4];
        if (base + 4 <= NE) {
            int4 d4 = *(const int4*)(ei + NE + base);
            ds4[0] = d4.x; ds4[1] = d4.y; ds4[2] = d4.z; ds4[3] = d4.w;
        } else {
            for (int k = 0; k < 4; ++k) ds4[k] = (base + k < NE) ? ei[NE + base + k] : -1;
        }
        #pragma unroll
        for (int k = 0; k < 4; ++k) {
            int dst = ds4[k];
            if (dst < 0) continue;
            if (!(tbl[(dst >> 5) & 31] & (1u << (dst & 31)))) continue;  // bloom reject
            int e = (int)base + k;
            int r = -1, src = 0;
            for (int b = 0; b < B; ++b) {
                if (dst == curl[b]) {
                    if (r < 0) { r = et[e]; src = ei[e]; }
                    atomicAdd(&wcnt[b * R + r], 1.0f);
                    int p = atomicAdd(&lcnt, 1);
                    if (p < 64) loc[p] = int2{src, b * R + r};
                }
            }
        }
    }
    __syncthreads();
    int n = lcnt; if (n > 64) n = 64;
    for (int m = 0; m < n; ++m) {
        int2 pr = loc[m];
        const float* xs = x + (long)pr.x * D;
        float* sm = wsum + (long)pr.y * D;
        for (int t = tid; t < D; t += 256) atomicAdd(&sm[t], xs[t]);
    }
}

// Proven (R7): 72 blocks x 25-row K-chunks of U[32x1800] @ M[1800x300]; no flag.
__global__ __launch_bounds__(320) void rgcn_hc(
        const float* __restrict__ x, const int* __restrict__ cur,
        const float* __restrict__ comp, const float* __restrict__ root,
        const float* __restrict__ basis, const float* __restrict__ wsum,
        const float* __restrict__ wcnt, float* __restrict__ hcf) {
    int kc = blockIdx.x, t = threadIdx.x;
    __shared__ float uL[800];       // 32 b x 25 k
    __shared__ float inv[B * R];
    __shared__ float cmp[R * R];
    if (t < B * R) inv[t] = 1.0f / fmaxf(wcnt[t], 1.0f);
    if (t >= 160 && t < 160 + R * R) cmp[t - 160] = comp[t - 160];
    __syncthreads();
    int d0 = kc * 25;
    if (d0 < 300) {
        for (int i = t; i < 800; i += 320) {
            int b = i / 25, dd = i - b * 25;
            uL[i] = x[(long)cur[b] * D + d0 + dd];
        }
    } else {
        int g0 = d0 - 300;
        int bb = g0 / 300, t0 = g0 - bb * 300;   // 25 | 300, no straddle
        for (int i = t; i < 800; i += 320) {
            int b = i / 25, dd = i - b * 25;
            float a = 0.f;
            #pragma unroll
            for (int r = 0; r < R; ++r)
                a = fmaf(cmp[r * R + bb] * inv[b * R + r], wsum[(long)(b * R + r) * D + t0 + dd], a);
            uL[i] = a;
        }
    }
    __syncthreads();
    if (t < D) {
        const float* Mb = (d0 < 300) ? (root + (long)d0 * D) : (basis + (long)(d0 - 300) * D);
        float acc[B] = {};
        #pragma unroll 5
        for (int i = 0; i < 25; ++i) {
            float m = Mb[(long)i * D + t];
            #pragma unroll
            for (int b = 0; b < B; ++b) acc[b] = fmaf(uL[b * 25 + i], m, acc[b]);
        }
        for (int b = 0; b < B; ++b) atomicAdd(&hcf[b * D + t], acc[b]);
    }
}

// Head GEMM v4: block stages 64 CONTIGUOUS W rows -> LDS bf16 (streaming-
// friendly HBM pattern, deep MLP), then 4 waves of 16j x 32b MFMA from LDS.
__global__ __launch_bounds__(256) void head_gemm(
    const float* __restrict__ hcf, const float* __restrict__ bias,
    const float* __restrict__ wg, const float* __restrict__ bg,
    const float* __restrict__ wsn, const float* __restrict__ bsn,
    float* __restrict__ out, float2* __restrict__ pm2) {
    __shared__ __bf16 hcbL[32 * HST];   // 20.7 KB
    __shared__ __bf16 wtL[WT * HST];    // 41.5 KB
    int tid = threadIdx.x;
    int j0 = blockIdx.x * WT;

    // stage hc (bias+relu+bf16); kk>=300 zeroed
    for (int i = tid; i < 32 * HST; i += 256) {
        int b = i / HST, kk = i - b * HST;
        float v = 0.f;
        if (kk < D) v = fmaxf(hcf[b * D + kk] + bias[kk], 0.f);
        hcbL[i] = (__bf16)v;
    }
    // stage W tile: 64 rows x 40 groups of 8 floats (contiguous per block)
    for (int task = tid; task < WT * NGRP; task += 256) {
        int rr = task / NGRP, g = task - rr * NGRP;
        int row = j0 + rr; if (row >= NROWS) row = NROWS - 1;
        const float* wr = (row < NG) ? (wg + (long)row * D) : (wsn + (long)(row - NG) * D);
        float4 w0 = float4{0.f,0.f,0.f,0.f}, w1 = float4{0.f,0.f,0.f,0.f};
        if (g < 37)       { w0 = *(const float4*)(wr + g * 8); w1 = *(const float4*)(wr + g * 8 + 4); }
        else if (g == 37) { w0 = *(const float4*)(wr + 296); }   // k 296..299, rest zero
        bf16x8 a;
        a[0]=(__bf16)w0.x; a[1]=(__bf16)w0.y; a[2]=(__bf16)w0.z; a[3]=(__bf16)w0.w;
        a[4]=(__bf16)w1.x; a[5]=(__bf16)w1.y; a[6]=(__bf16)w1.z; a[7]=(__bf16)w1.w;
        *(bf16x8*)(wtL + rr * HST + g * 8) = a;
    }
    __syncthreads();

    int wid = tid >> 6, l = tid & 63, ln = l & 15, og = l >> 4;
    int jt = blockIdx.x * 4 + wid;
    if (jt >= NT16) return;          // no barriers after this point
    int jw = jt * 16;

    const __bf16* arow  = wtL + (wid * 16 + ln) * HST + og * 8;
    const __bf16* hrow0 = hcbL + ln * HST + og * 8;
    const __bf16* hrow1 = hcbL + (16 + ln) * HST + og * 8;
    f32x4 acc0 = {}, acc1 = {};
    #pragma unroll
    for (int s = 0; s < 10; ++s) {
        bf16x8 a = *(const bf16x8*)(arow + 32 * s);
        acc0 = __builtin_amdgcn_mfma_f32_16x16x32_bf16(a, *(const bf16x8*)(hrow0 + 32 * s), acc0, 0, 0, 0);
        acc1 = __builtin_amdgcn_mfma_f32_16x16x32_bf16(a, *(const bf16x8*)(hrow1 + 32 * s), acc1, 0, 0, 0);
    }

    // epilogue (verified mapping: col=b, row=og*4+r)
    int b0 = ln, b1 = 16 + ln;
    float m0 = -3.0e38f, s0 = 0.f, m1 = -3.0e38f, s1 = 0.f;
    float m2 = -3.0e38f, s2 = 0.f, m3 = -3.0e38f, s3 = 0.f;
    #pragma unroll
    for (int r = 0; r < 4; ++r) {
        int j = jw + og * 4 + r;
        float bv = (j < NG) ? bg[j] : bsn[j - NG];
        float v0 = acc0[r] + bv;
        float v1 = acc1[r] + bv;
        float* op0 = (j < NG) ? (out + (long)b0 * NG + j)
                              : (out + (long)B * NG + (long)b0 * NS + (j - NG));
        float* op1 = (j < NG) ? (out + (long)b1 * NG + j)
                              : (out + (long)B * NG + (long)b1 * NS + (j - NG));
        *op0 = v0;
        *op1 = v1;
        if (j < NG) { online_upd(m0, s0, v0); online_upd(m2, s2, v1); }
        else        { online_upd(m1, s1, v0); online_upd(m3, s3, v1); }
    }
    #pragma unroll
    for (int o = 16; o <= 32; o <<= 1) {
        float tm, ts;
        tm = __shfl_xor(m0, o); ts = __shfl_xor(s0, o); online_merge(m0, s0, tm, ts);
        tm = __shfl_xor(m1, o); ts = __shfl_xor(s1, o); online_merge(m1, s1, tm, ts);
        tm = __shfl_xor(m2, o); ts = __shfl_xor(s2, o); online_merge(m2, s2, tm, ts);
        tm = __shfl_xor(m3, o); ts = __shfl_xor(s3, o); online_merge(m3, s3, tm, ts);
    }
    if (og == 0) {
        pm2[(long)b0 * NT16 + jt]       = float2{m0, s0};
        pm2[(long)(B + b0) * NT16 + jt] = float2{m1, s1};
        pm2[(long)b1 * NT16 + jt]       = float2{m2, s2};
        pm2[(long)(B + b1) * NT16 + jt] = float2{m3, s3};
    }
}

// Fused lse reduce (L2/L3-hot strip, redundant per 25 chunk-blocks) + subtract.
__global__ __launch_bounds__(256) void lse_sub(float* __restrict__ out,
                                               const float2* __restrict__ pm2) {
    int rw = blockIdx.x / 25, c = blockIdx.x % 25;
    int tid = threadIdx.x;
    const float2* pr = pm2 + (long)rw * NT16;
    float m = -3.0e38f, s = 0.f;
    for (int i = tid; i < NT16; i += 256) { float2 e = pr[i]; online_merge(m, s, e.x, e.y); }
    #pragma unroll
    for (int o = 32; o; o >>= 1) {
        float om = __shfl_xor(m, o), os = __shfl_xor(s, o);
        online_merge(m, s, om, os);
    }
    __shared__ float sm[4], ss[4];
    __shared__ float lseS;
    if ((tid & 63) == 0) { sm[tid >> 6] = m; ss[tid >> 6] = s; }
    __syncthreads();
    if (tid == 0) {
        float M = sm[0], S = ss[0];
        for (int w = 1; w < 4; ++w) online_merge(M, S, sm[w], ss[w]);
        lseS = M + __logf(S);
    }
    __syncthreads();
    float l = lseS;
    float4* o4 = (float4*)out + (long)rw * 6250 + c * 250;
    if (tid < 250) { float4 v = o4[tid]; v.x -= l; v.y -= l; v.z -= l; v.w -= l; o4[tid] = v; }
}

extern "C" void kernel_launch(void* const* d_in, const int* in_sizes, int n_in,
                              void* d_out, int out_size, void* d_ws, size_t ws_size,
                              hipStream_t stream) {
    const float* x     = (const float*)d_in[0];
    const int*   ei    = (const int*)d_in[1];
    const int*   et    = (const int*)d_in[2];
    const int*   cur   = (const int*)d_in[3];
    const float* basis = (const float*)d_in[4];
    const float* comp  = (const float*)d_in[5];
    const float* root  = (const float*)d_in[6];
    const float* bias  = (const float*)d_in[7];
    const float* wg    = (const float*)d_in[8];
    const float* bgl   = (const float*)d_in[9];
    const float* wsn   = (const float*)d_in[10];
    const float* bsn   = (const float*)d_in[11];
    float* out  = (float*)d_out;
    float* wsf  = (float*)d_ws;
    float*  wsum = wsf;                        // [0, 48000)
    float*  wcnt = wsf + 48000;                // [48000, 48160)
    float*  hcf  = wsf + 48160;                // [48160, 57760)
    float2* pm2  = (float2*)(wsf + 57760);     // 64 x 3125

    zero_ws<<<57, 256, 0, stream>>>((float4*)d_ws);
    scan_accum<<<977, 256, 0, stream>>>(ei, et, cur, x, wsum, wcnt);
    rgcn_hc<<<72, 320, 0, stream>>>(x, cur, comp, root, basis, wsum, wcnt, hcf);
    head_gemm<<<(NROWS + WT - 1) / WT, 256, 0, stream>>>(hcf, bias, wg, bgl, wsn, bsn, out, pm2);
    lse_sub<<<1600, 256, 0, stream>>>(out, pm2);
}

// Round 14
// 91.811 us; speedup vs baseline: 1.1104x; 1.1104x over previous
//
#include <hip/hip_runtime.h>
#include <hip/hip_bf16.h>
#include <math.h>

#define D 300
#define R 5
#define NE 1000000
#define B 32
#define NG 25000
#define NS 25000
#define NROWS 50000
#define NT16 3125      // 16-row j-tiles (50000 = 3125*16)
#define HST 324        // hcbL LDS row stride in bf16 (648 B; measured 0 conflicts)

typedef __bf16 bf16x8 __attribute__((ext_vector_type(8)));
typedef float f32x4 __attribute__((ext_vector_type(4)));

// ws layout (floats):
//   wsum [0, 48000)  wcnt [48000, 48160)  hcf [48160, 57760)
//   pm2  float2 at 57760: 64 x 3125 -> [57760, 457760)
//   W2   bf16 at 457760: 3125 tiles x 5120 bf16 (32 MB) -> frag-major W

__device__ __forceinline__ void online_upd(float& m, float& s, float v) {
    if (v > m) { s = s * __expf(m - v) + 1.0f; m = v; }
    else       { s += __expf(v - m); }
}
__device__ __forceinline__ void online_merge(float& m, float& s, float om, float os) {
    float M = fmaxf(m, om);
    s = s * __expf(m - M) + os * __expf(om - M);
    m = M;
}

__global__ void zero_ws(float4* __restrict__ p) {
    int i = blockIdx.x * 256 + threadIdx.x;
    if (i < 14440) p[i] = float4{0.f, 0.f, 0.f, 0.f};  // wsum|wcnt|hcf
}

// Proven (R4-R7): bloom dst scan, LDS-compact matches, coalesced 300-float row-adds.
__global__ __launch_bounds__(256) void scan_accum(
        const int* __restrict__ ei, const int* __restrict__ et,
        const int* __restrict__ cur, const float* __restrict__ x,
        float* __restrict__ wsum, float* __restrict__ wcnt) {
    __shared__ unsigned int tbl[32];
    __shared__ int curl[B];
    __shared__ int lcnt;
    __shared__ int2 loc[64];
    int tid = threadIdx.x;
    if (tid < 32) tbl[tid] = 0u;
    if (tid == 0) lcnt = 0;
    __syncthreads();
    if (tid < B) { int c = cur[tid]; curl[tid] = c; atomicOr(&tbl[(c >> 5) & 31], 1u << (c & 31)); }
    __syncthreads();
    long base = ((long)blockIdx.x * 256 + tid) * 4;
    if (base < NE) {
        int ds4[4];
        if (base + 4 <= NE) {
            int4 d4 = *(const int4*)(ei + NE + base);
            ds4[0] = d4.x; ds4[1] = d4.y; ds4[2] = d4.z; ds4[3] = d4.w;
        } else {
            for (int k = 0; k < 4; ++k) ds4[k] = (base + k < NE) ? ei[NE + base + k] : -1;
        }
        #pragma unroll
        for (int k = 0; k < 4; ++k) {
            int dst = ds4[k];
            if (dst < 0) continue;
            if (!(tbl[(dst >> 5) & 31] & (1u << (dst & 31)))) continue;  // bloom reject
            int e = (int)base + k;
            int r = -1, src = 0;
            for (int b = 0; b < B; ++b) {
                if (dst == curl[b]) {
                    if (r < 0) { r = et[e]; src = ei[e]; }
                    atomicAdd(&wcnt[b * R + r], 1.0f);
                    int p = atomicAdd(&lcnt, 1);
                    if (p < 64) loc[p] = int2{src, b * R + r};
                }
            }
        }
    }
    __syncthreads();
    int n = lcnt; if (n > 64) n = 64;
    for (int m = 0; m < n; ++m) {
        int2 pr = loc[m];
        const float* xs = x + (long)pr.x * D;
        float* sm = wsum + (long)pr.y * D;
        for (int t = tid; t < D; t += 256) atomicAdd(&sm[t], xs[t]);
    }
}

// Proven (R7): 72 blocks x 25-row K-chunks of U[32x1800] @ M[1800x300]; no flag.
__global__ __launch_bounds__(320) void rgcn_hc(
        const float* __restrict__ x, const int* __restrict__ cur,
        const float* __restrict__ comp, const float* __restrict__ root,
        const float* __restrict__ basis, const float* __restrict__ wsum,
        const float* __restrict__ wcnt, float* __restrict__ hcf) {
    int kc = blockIdx.x, t = threadIdx.x;
    __shared__ float uL[800];       // 32 b x 25 k
    __shared__ float inv[B * R];
    __shared__ float cmp[R * R];
    if (t < B * R) inv[t] = 1.0f / fmaxf(wcnt[t], 1.0f);
    if (t >= 160 && t < 160 + R * R) cmp[t - 160] = comp[t - 160];
    __syncthreads();
    int d0 = kc * 25;
    if (d0 < 300) {
        for (int i = t; i < 800; i += 320) {
            int b = i / 25, dd = i - b * 25;
            uL[i] = x[(long)cur[b] * D + d0 + dd];
        }
    } else {
        int g0 = d0 - 300;
        int bb = g0 / 300, t0 = g0 - bb * 300;   // 25 | 300, no straddle
        for (int i = t; i < 800; i += 320) {
            int b = i / 25, dd = i - b * 25;
            float a = 0.f;
            #pragma unroll
            for (int r = 0; r < R; ++r)
                a = fmaf(cmp[r * R + bb] * inv[b * R + r], wsum[(long)(b * R + r) * D + t0 + dd], a);
            uL[i] = a;
        }
    }
    __syncthreads();
    if (t < D) {
        const float* Mb = (d0 < 300) ? (root + (long)d0 * D) : (basis + (long)(d0 - 300) * D);
        float acc[B] = {};
        #pragma unroll 5
        for (int i = 0; i < 25; ++i) {
            float m = Mb[(long)i * D + t];
            #pragma unroll
            for (int b = 0; b < B; ++b) acc[b] = fmaf(uL[b * 25 + i], m, acc[b]);
        }
        for (int b = 0; b < B; ++b) atomicAdd(&hcf[b * D + t], acc[b]);
    }
}

// W pack: block jt reads 16 CONSECUTIVE W rows (one contiguous 76.8 KB chunk,
// memcpy-shaped), LDS-transposes, writes frag-major bf16: W2[jt][s][lane][8].
__global__ __launch_bounds__(256) void w_pack(
        const float* __restrict__ wg, const float* __restrict__ wsn,
        __bf16* __restrict__ W2) {
    __shared__ float tf[16 * 320];  // 20.5 KB
    int tid = threadIdx.x;
    int r0 = blockIdx.x * 16;
    // zero pad cols 300..319
    for (int i = tid; i < 16 * 20; i += 256) {
        int row = i / 20, q = i - row * 20;
        tf[row * 320 + 300 + q] = 0.f;
    }
    // read 16 rows x 75 float4 (contiguous across the 16-row chunk)
    for (int idx = tid; idx < 1200; idx += 256) {
        int row = idx / 75, q = idx - row * 75;
        int r = r0 + row;
        const float* wr = (r < NG) ? (wg + (long)r * D) : (wsn + (long)(r - NG) * D);
        *(float4*)(tf + row * 320 + q * 4) = *(const float4*)(wr + q * 4);
    }
    __syncthreads();
    // write 640 frag groups (s=t>>6, lane=t&63), contiguous 16B stores
    __bf16* dst = W2 + (long)blockIdx.x * 5120;
    for (int t2 = tid; t2 < 640; t2 += 256) {
        int s = t2 >> 6, l = t2 & 63;
        int ln = l & 15, og = l >> 4;
        const float* src = tf + ln * 320 + og * 8 + 32 * s;
        bf16x8 a;
        #pragma unroll
        for (int i = 0; i < 8; ++i) a[i] = (__bf16)src[i];
        *(bf16x8*)(dst + (t2 << 3)) = a;
    }
}

// Head GEMM v5: A-frags from frag-major W2 (sequential coalesced 1KB wave-loads,
// L3-hot), B-frags from hc in LDS. Wave = 16 j x all 32 b.
__global__ __launch_bounds__(256) void head_gemm(
    const float* __restrict__ hcf, const float* __restrict__ bias,
    const __bf16* __restrict__ W2, const float* __restrict__ bg,
    const float* __restrict__ bsn, float* __restrict__ out, float2* __restrict__ pm2) {
    __shared__ __bf16 hcbL[32 * HST];   // 20.7 KB
    int tid = threadIdx.x;
    for (int i = tid; i < 32 * HST; i += 256) {
        int b = i / HST, kk = i - b * HST;
        float v = 0.f;
        if (kk < D) v = fmaxf(hcf[b * D + kk] + bias[kk], 0.f);
        hcbL[i] = (__bf16)v;
    }
    __syncthreads();

    int wid = tid >> 6, l = tid & 63, ln = l & 15, og = l >> 4;
    int jt = blockIdx.x * 4 + wid;
    if (jt >= NT16) return;
    int jw = jt * 16;

    const __bf16* wp = W2 + (long)jt * 5120 + l * 8;
    bf16x8 af[10];
    #pragma unroll
    for (int s = 0; s < 10; ++s) af[s] = *(const bf16x8*)(wp + s * 512);

    const __bf16* hrow0 = hcbL + ln * HST + og * 8;
    const __bf16* hrow1 = hcbL + (16 + ln) * HST + og * 8;
    f32x4 acc0 = {}, acc1 = {};
    #pragma unroll
    for (int s = 0; s < 10; ++s) {
        acc0 = __builtin_amdgcn_mfma_f32_16x16x32_bf16(af[s], *(const bf16x8*)(hrow0 + 32 * s), acc0, 0, 0, 0);
        acc1 = __builtin_amdgcn_mfma_f32_16x16x32_bf16(af[s], *(const bf16x8*)(hrow1 + 32 * s), acc1, 0, 0, 0);
    }

    // epilogue (verified mapping: col=b, row=og*4+r)
    int b0 = ln, b1 = 16 + ln;
    float m0 = -3.0e38f, s0 = 0.f, m1 = -3.0e38f, s1 = 0.f;
    float m2 = -3.0e38f, s2 = 0.f, m3 = -3.0e38f, s3 = 0.f;
    #pragma unroll
    for (int r = 0; r < 4; ++r) {
        int j = jw + og * 4 + r;
        float bv = (j < NG) ? bg[j] : bsn[j - NG];
        float v0 = acc0[r] + bv;
        float v1 = acc1[r] + bv;
        float* op0 = (j < NG) ? (out + (long)b0 * NG + j)
                              : (out + (long)B * NG + (long)b0 * NS + (j - NG));
        float* op1 = (j < NG) ? (out + (long)b1 * NG + j)
                              : (out + (long)B * NG + (long)b1 * NS + (j - NG));
        *op0 = v0;
        *op1 = v1;
        if (j < NG) { online_upd(m0, s0, v0); online_upd(m2, s2, v1); }
        else        { online_upd(m1, s1, v0); online_upd(m3, s3, v1); }
    }
    #pragma unroll
    for (int o = 16; o <= 32; o <<= 1) {
        float tm, ts;
        tm = __shfl_xor(m0, o); ts = __shfl_xor(s0, o); online_merge(m0, s0, tm, ts);
        tm = __shfl_xor(m1, o); ts = __shfl_xor(s1, o); online_merge(m1, s1, tm, ts);
        tm = __shfl_xor(m2, o); ts = __shfl_xor(s2, o); online_merge(m2, s2, tm, ts);
        tm = __shfl_xor(m3, o); ts = __shfl_xor(s3, o); online_merge(m3, s3, tm, ts);
    }
    if (og == 0) {
        pm2[(long)b0 * NT16 + jt]       = float2{m0, s0};
        pm2[(long)(B + b0) * NT16 + jt] = float2{m1, s1};
        pm2[(long)b1 * NT16 + jt]       = float2{m2, s2};
        pm2[(long)(B + b1) * NT16 + jt] = float2{m3, s3};
    }
}

// Fused lse reduce (L2/L3-hot strip, redundant per 25 chunk-blocks) + subtract.
__global__ __launch_bounds__(256) void lse_sub(float* __restrict__ out,
                                               const float2* __restrict__ pm2) {
    int rw = blockIdx.x / 25, c = blockIdx.x % 25;
    int tid = threadIdx.x;
    const float2* pr = pm2 + (long)rw * NT16;
    float m = -3.0e38f, s = 0.f;
    for (int i = tid; i < NT16; i += 256) { float2 e = pr[i]; online_merge(m, s, e.x, e.y); }
    #pragma unroll
    for (int o = 32; o; o >>= 1) {
        float om = __shfl_xor(m, o), os = __shfl_xor(s, o);
        online_merge(m, s, om, os);
    }
    __shared__ float sm[4], ss[4];
    __shared__ float lseS;
    if ((tid & 63) == 0) { sm[tid >> 6] = m; ss[tid >> 6] = s; }
    __syncthreads();
    if (tid == 0) {
        float M = sm[0], S = ss[0];
        for (int w = 1; w < 4; ++w) online_merge(M, S, sm[w], ss[w]);
        lseS = M + __logf(S);
    }
    __syncthreads();
    float l = lseS;
    float4* o4 = (float4*)out + (long)rw * 6250 + c * 250;
    if (tid < 250) { float4 v = o4[tid]; v.x -= l; v.y -= l; v.z -= l; v.w -= l; o4[tid] = v; }
}

extern "C" void kernel_launch(void* const* d_in, const int* in_sizes, int n_in,
                              void* d_out, int out_size, void* d_ws, size_t ws_size,
                              hipStream_t stream) {
    const float* x     = (const float*)d_in[0];
    const int*   ei    = (const int*)d_in[1];
    const int*   et    = (const int*)d_in[2];
    const int*   cur   = (const int*)d_in[3];
    const float* basis = (const float*)d_in[4];
    const float* comp  = (const float*)d_in[5];
    const float* root  = (const float*)d_in[6];
    const float* bias  = (const float*)d_in[7];
    const float* wg    = (const float*)d_in[8];
    const float* bgl   = (const float*)d_in[9];
    const float* wsn   = (const float*)d_in[10];
    const float* bsn   = (const float*)d_in[11];
    float* out  = (float*)d_out;
    float* wsf  = (float*)d_ws;
    float*  wsum = wsf;                        // [0, 48000)
    float*  wcnt = wsf + 48000;                // [48000, 48160)
    float*  hcf  = wsf + 48160;                // [48160, 57760)
    float2* pm2  = (float2*)(wsf + 57760);     // 64 x 3125
    __bf16* W2   = (__bf16*)(wsf + 457760);    // 3125 x 5120 bf16 (32 MB)

    zero_ws<<<57, 256, 0, stream>>>((float4*)d_ws);
    scan_accum<<<977, 256, 0, stream>>>(ei, et, cur, x, wsum, wcnt);
    rgcn_hc<<<72, 320, 0, stream>>>(x, cur, comp, root, basis, wsum, wcnt, hcf);
    w_pack<<<NT16, 256, 0, stream>>>(wg, wsn, W2);
    head_gemm<<<(NT16 + 3) / 4, 256, 0, stream>>>(hcf, bias, W2, bgl, bsn, out, pm2);
    lse_sub<<<1600, 256, 0, stream>>>(out, pm2);
}

// Round 15
// 71.379 us; speedup vs baseline: 1.4282x; 1.2862x over previous
//
#include <hip/hip_runtime.h>
#include <hip/hip_bf16.h>
#include <math.h>

#define D 300
#define R 5
#define NE 1000000
#define B 32
#define NG 25000
#define NS 25000
#define NROWS 50000
#define NT16 3125      // 16-row j-tiles (50000 = 3125*16)
#define NBLK2 782      // head blocks = ceil(3125/4)
#define XQ 97          // NBLK2 / 8
#define XR 6           // NBLK2 % 8
#define HST 324        // hcbL LDS row stride in bf16 (648 B; measured 0 conflicts)

typedef __bf16 bf16x8 __attribute__((ext_vector_type(8)));
typedef float f32x4 __attribute__((ext_vector_type(4)));

// ws layout (floats):
//   wsum [0, 48000)  wcnt [48000, 48160)  hcf [48160, 57760)
//   pm2  float2 at 57760: 64 rows x 782 blocks -> [57760, 182880)

__device__ __forceinline__ void online_upd(float& m, float& s, float v) {
    if (v > m) { s = s * __expf(m - v) + 1.0f; m = v; }
    else       { s += __expf(v - m); }
}
__device__ __forceinline__ void online_merge(float& m, float& s, float om, float os) {
    float M = fmaxf(m, om);
    s = s * __expf(m - M) + os * __expf(om - M);
    m = M;
}

__global__ void zero_ws(float4* __restrict__ p) {
    int i = blockIdx.x * 256 + threadIdx.x;
    if (i < 14440) p[i] = float4{0.f, 0.f, 0.f, 0.f};  // wsum|wcnt|hcf
}

// Proven (R4-R7): bloom dst scan, LDS-compact matches, coalesced 300-float row-adds.
__global__ __launch_bounds__(256) void scan_accum(
        const int* __restrict__ ei, const int* __restrict__ et,
        const int* __restrict__ cur, const float* __restrict__ x,
        float* __restrict__ wsum, float* __restrict__ wcnt) {
    __shared__ unsigned int tbl[32];
    __shared__ int curl[B];
    __shared__ int lcnt;
    __shared__ int2 loc[64];
    int tid = threadIdx.x;
    if (tid < 32) tbl[tid] = 0u;
    if (tid == 0) lcnt = 0;
    __syncthreads();
    if (tid < B) { int c = cur[tid]; curl[tid] = c; atomicOr(&tbl[(c >> 5) & 31], 1u << (c & 31)); }
    __syncthreads();
    long base = ((long)blockIdx.x * 256 + tid) * 4;
    if (base < NE) {
        int ds4[4];
        if (base + 4 <= NE) {
            int4 d4 = *(const int4*)(ei + NE + base);
            ds4[0] = d4.x; ds4[1] = d4.y; ds4[2] = d4.z; ds4[3] = d4.w;
        } else {
            for (int k = 0; k < 4; ++k) ds4[k] = (base + k < NE) ? ei[NE + base + k] : -1;
        }
        #pragma unroll
        for (int k = 0; k < 4; ++k) {
            int dst = ds4[k];
            if (dst < 0) continue;
            if (!(tbl[(dst >> 5) & 31] & (1u << (dst & 31)))) continue;  // bloom reject
            int e = (int)base + k;
            int r = -1, src = 0;
            for (int b = 0; b < B; ++b) {
                if (dst == curl[b]) {
                    if (r < 0) { r = et[e]; src = ei[e]; }
                    atomicAdd(&wcnt[b * R + r], 1.0f);
                    int p = atomicAdd(&lcnt, 1);
                    if (p < 64) loc[p] = int2{src, b * R + r};
                }
            }
        }
    }
    __syncthreads();
    int n = lcnt; if (n > 64) n = 64;
    for (int m = 0; m < n; ++m) {
        int2 pr = loc[m];
        const float* xs = x + (long)pr.x * D;
        float* sm = wsum + (long)pr.y * D;
        for (int t = tid; t < D; t += 256) atomicAdd(&sm[t], xs[t]);
    }
}

// Proven (R7): 72 blocks x 25-row K-chunks of U[32x1800] @ M[1800x300]; no flag.
__global__ __launch_bounds__(320) void rgcn_hc(
        const float* __restrict__ x, const int* __restrict__ cur,
        const float* __restrict__ comp, const float* __restrict__ root,
        const float* __restrict__ basis, const float* __restrict__ wsum,
        const float* __restrict__ wcnt, float* __restrict__ hcf) {
    int kc = blockIdx.x, t = threadIdx.x;
    __shared__ float uL[800];       // 32 b x 25 k
    __shared__ float inv[B * R];
    __shared__ float cmp[R * R];
    if (t < B * R) inv[t] = 1.0f / fmaxf(wcnt[t], 1.0f);
    if (t >= 160 && t < 160 + R * R) cmp[t - 160] = comp[t - 160];
    __syncthreads();
    int d0 = kc * 25;
    if (d0 < 300) {
        for (int i = t; i < 800; i += 320) {
            int b = i / 25, dd = i - b * 25;
            uL[i] = x[(long)cur[b] * D + d0 + dd];
        }
    } else {
        int g0 = d0 - 300;
        int bb = g0 / 300, t0 = g0 - bb * 300;   // 25 | 300, no straddle
        for (int i = t; i < 800; i += 320) {
            int b = i / 25, dd = i - b * 25;
            float a = 0.f;
            #pragma unroll
            for (int r = 0; r < R; ++r)
                a = fmaf(cmp[r * R + bb] * inv[b * R + r], wsum[(long)(b * R + r) * D + t0 + dd], a);
            uL[i] = a;
        }
    }
    __syncthreads();
    if (t < D) {
        const float* Mb = (d0 < 300) ? (root + (long)d0 * D) : (basis + (long)(d0 - 300) * D);
        float acc[B] = {};
        #pragma unroll 5
        for (int i = 0; i < 25; ++i) {
            float m = Mb[(long)i * D + t];
            #pragma unroll
            for (int b = 0; b < B; ++b) acc[b] = fmaf(uL[b * 25 + i], m, acc[b]);
        }
        for (int b = 0; b < B; ++b) atomicAdd(&hcf[b * D + t], acc[b]);
    }
}

// Head GEMM v6: R12 structure + XCD-bijective block swizzle (each XCD gets a
// contiguous ~7.5 MB W slice) + per-block pm2 wave-merge (pm2 [64][782]).
__global__ __launch_bounds__(256) void head_gemm(
    const float* __restrict__ hcf, const float* __restrict__ bias,
    const float* __restrict__ wg, const float* __restrict__ bg,
    const float* __restrict__ wsn, const float* __restrict__ bsn,
    float* __restrict__ out, float2* __restrict__ pm2) {
    __shared__ __bf16 hcbL[32 * HST];        // 20.7 KB
    __shared__ float2 sred[4][4][16];        // [wave][kind][ln]
    int tid = threadIdx.x;
    for (int i = tid; i < 32 * HST; i += 256) {
        int b = i / HST, kk = i - b * HST;
        float v = 0.f;
        if (kk < D) v = fmaxf(hcf[b * D + kk] + bias[kk], 0.f);
        hcbL[i] = (__bf16)v;
    }
    __syncthreads();

    // bijective XCD swizzle: xcd = orig % 8 owns contiguous logical chunk
    int orig = blockIdx.x;
    int xcd = orig & 7, off = orig >> 3;
    int wgid = (xcd < XR ? xcd * (XQ + 1) : XR * (XQ + 1) + (xcd - XR) * XQ) + off;

    int wid = tid >> 6, l = tid & 63, ln = l & 15, og = l >> 4;
    int jt = wgid * 4 + wid;
    bool valid = jt < NT16;
    int jtc = valid ? jt : NT16 - 1;
    int jw = jtc * 16;
    int row = jw + ln;
    const float* wrow = ((row < NG) ? (wg + (long)row * D) : (wsn + (long)(row - NG) * D)) + og * 8;

    const __bf16* hrow0 = hcbL + ln * HST + og * 8;
    const __bf16* hrow1 = hcbL + (16 + ln) * HST + og * 8;
    f32x4 acc0 = {}, acc1 = {};
    #pragma unroll
    for (int s = 0; s < 9; ++s) {
        float4 w0 = *(const float4*)(wrow + 32 * s);
        float4 w1 = *(const float4*)(wrow + 32 * s + 4);
        bf16x8 a;
        a[0]=(__bf16)w0.x; a[1]=(__bf16)w0.y; a[2]=(__bf16)w0.z; a[3]=(__bf16)w0.w;
        a[4]=(__bf16)w1.x; a[5]=(__bf16)w1.y; a[6]=(__bf16)w1.z; a[7]=(__bf16)w1.w;
        acc0 = __builtin_amdgcn_mfma_f32_16x16x32_bf16(a, *(const bf16x8*)(hrow0 + 32 * s), acc0, 0, 0, 0);
        acc1 = __builtin_amdgcn_mfma_f32_16x16x32_bf16(a, *(const bf16x8*)(hrow1 + 32 * s), acc1, 0, 0, 0);
    }
    {   // tail: og0 -> k288..295; og1 -> k296..299 (+zeros); og2/3 -> zeros
        float4 w0 = float4{0.f,0.f,0.f,0.f}, w1 = float4{0.f,0.f,0.f,0.f};
        if (og == 0) { w0 = *(const float4*)(wrow + 288); w1 = *(const float4*)(wrow + 292); }
        else if (og == 1) { w0 = *(const float4*)(wrow + 288); }
        bf16x8 a;
        a[0]=(__bf16)w0.x; a[1]=(__bf16)w0.y; a[2]=(__bf16)w0.z; a[3]=(__bf16)w0.w;
        a[4]=(__bf16)w1.x; a[5]=(__bf16)w1.y; a[6]=(__bf16)w1.z; a[7]=(__bf16)w1.w;
        acc0 = __builtin_amdgcn_mfma_f32_16x16x32_bf16(a, *(const bf16x8*)(hrow0 + 288), acc0, 0, 0, 0);
        acc1 = __builtin_amdgcn_mfma_f32_16x16x32_bf16(a, *(const bf16x8*)(hrow1 + 288), acc1, 0, 0, 0);
    }

    // epilogue (verified mapping: col=b, row=og*4+r)
    int b0 = ln, b1 = 16 + ln;
    float m0 = -3.0e38f, s0 = 0.f, m1 = -3.0e38f, s1 = 0.f;
    float m2 = -3.0e38f, s2 = 0.f, m3 = -3.0e38f, s3 = 0.f;
    if (valid) {
        #pragma unroll
        for (int r = 0; r < 4; ++r) {
            int j = jw + og * 4 + r;
            float bv = (j < NG) ? bg[j] : bsn[j - NG];
            float v0 = acc0[r] + bv;
            float v1 = acc1[r] + bv;
            float* op0 = (j < NG) ? (out + (long)b0 * NG + j)
                                  : (out + (long)B * NG + (long)b0 * NS + (j - NG));
            float* op1 = (j < NG) ? (out + (long)b1 * NG + j)
                                  : (out + (long)B * NG + (long)b1 * NS + (j - NG));
            *op0 = v0;
            *op1 = v1;
            if (j < NG) { online_upd(m0, s0, v0); online_upd(m2, s2, v1); }
            else        { online_upd(m1, s1, v0); online_upd(m3, s3, v1); }
        }
    }
    #pragma unroll
    for (int o = 16; o <= 32; o <<= 1) {
        float tm, ts;
        tm = __shfl_xor(m0, o); ts = __shfl_xor(s0, o); online_merge(m0, s0, tm, ts);
        tm = __shfl_xor(m1, o); ts = __shfl_xor(s1, o); online_merge(m1, s1, tm, ts);
        tm = __shfl_xor(m2, o); ts = __shfl_xor(s2, o); online_merge(m2, s2, tm, ts);
        tm = __shfl_xor(m3, o); ts = __shfl_xor(s3, o); online_merge(m3, s3, tm, ts);
    }
    if (l < 16) {
        sred[wid][0][ln] = float2{m0, s0};   // glob, b0
        sred[wid][1][ln] = float2{m1, s1};   // sense, b0
        sred[wid][2][ln] = float2{m2, s2};   // glob, b1
        sred[wid][3][ln] = float2{m3, s3};   // sense, b1
    }
    __syncthreads();
    if (tid < 64) {
        int k = tid >> 4, lnn = tid & 15;
        float m = -3.0e38f, s = 0.f;
        #pragma unroll
        for (int w = 0; w < 4; ++w) online_merge(m, s, sred[w][k][lnn].x, sred[w][k][lnn].y);
        int rw = (k & 1) * 32 + (k >> 1) * 16 + lnn;
        pm2[(long)rw * NBLK2 + wgid] = float2{m, s};
    }
}

// Fused lse reduce (782-entry strip, L2-hot) + subtract over a 1000-float chunk.
__global__ __launch_bounds__(256) void lse_sub(float* __restrict__ out,
                                               const float2* __restrict__ pm2) {
    int rw = blockIdx.x / 25, c = blockIdx.x % 25;
    int tid = threadIdx.x;
    const float2* pr = pm2 + (long)rw * NBLK2;
    float m = -3.0e38f, s = 0.f;
    for (int i = tid; i < NBLK2; i += 256) { float2 e = pr[i]; online_merge(m, s, e.x, e.y); }
    #pragma unroll
    for (int o = 32; o; o >>= 1) {
        float om = __shfl_xor(m, o), os = __shfl_xor(s, o);
        online_merge(m, s, om, os);
    }
    __shared__ float sm[4], ss[4];
    __shared__ float lseS;
    if ((tid & 63) == 0) { sm[tid >> 6] = m; ss[tid >> 6] = s; }
    __syncthreads();
    if (tid == 0) {
        float M = sm[0], S = ss[0];
        for (int w = 1; w < 4; ++w) online_merge(M, S, sm[w], ss[w]);
        lseS = M + __logf(S);
    }
    __syncthreads();
    float l = lseS;
    float4* o4 = (float4*)out + (long)rw * 6250 + c * 250;
    if (tid < 250) { float4 v = o4[tid]; v.x -= l; v.y -= l; v.z -= l; v.w -= l; o4[tid] = v; }
}

extern "C" void kernel_launch(void* const* d_in, const int* in_sizes, int n_in,
                              void* d_out, int out_size, void* d_ws, size_t ws_size,
                              hipStream_t stream) {
    const float* x     = (const float*)d_in[0];
    const int*   ei    = (const int*)d_in[1];
    const int*   et    = (const int*)d_in[2];
    const int*   cur   = (const int*)d_in[3];
    const float* basis = (const float*)d_in[4];
    const float* comp  = (const float*)d_in[5];
    const float* root  = (const float*)d_in[6];
    const float* bias  = (const float*)d_in[7];
    const float* wg    = (const float*)d_in[8];
    const float* bgl   = (const float*)d_in[9];
    const float* wsn   = (const float*)d_in[10];
    const float* bsn   = (const float*)d_in[11];
    float* out  = (float*)d_out;
    float* wsf  = (float*)d_ws;
    float*  wsum = wsf;                        // [0, 48000)
    float*  wcnt = wsf + 48000;                // [48000, 48160)
    float*  hcf  = wsf + 48160;                // [48160, 57760)
    float2* pm2  = (float2*)(wsf + 57760);     // 64 x 782

    zero_ws<<<57, 256, 0, stream>>>((float4*)d_ws);
    scan_accum<<<977, 256, 0, stream>>>(ei, et, cur, x, wsum, wcnt);
    rgcn_hc<<<72, 320, 0, stream>>>(x, cur, comp, root, basis, wsum, wcnt, hcf);
    head_gemm<<<NBLK2, 256, 0, stream>>>(hcf, bias, wg, bgl, wsn, bsn, out, pm2);
    lse_sub<<<1600, 256, 0, stream>>>(out, pm2);
}